// Round 3
// baseline (62872.784 us; speedup 1.0000x reference)
//
#include <hip/hip_runtime.h>
#include <hip/hip_cooperative_groups.h>
#include <math.h>

namespace cg = cooperative_groups;

#define T_STEPS 64
#define B_      256
#define EMB_    1024
#define ACT_    6
#define STOCH_  64
#define HID_    512
#define FEAT_   512
#define STATE_  576
#define G3      1536
#define NBLK    256
#define NTHR    512
#define TK      32
#define XPAD    68    // 272 B row, 16B aligned
#define WPAD    132   // 528 B row, 16B aligned
#define LOG2PI_ 1.8378770664093453

struct SmemT { float X[2][TK][XPAD]; float W[2][TK][WPAD]; };  // 51200 B

struct Params {
  const float *emb,*action,*reward,*eps;
  const float *Wih,*bih,*Whh,*bhh;
  const float *stW0,*stb0,*stW1,*stb1,*stW2,*stb2;
  const float *epW0,*epb0,*epW1,*epb1,*epW2,*epb2;
  const float *rpW0,*rpb0,*rpW1,*rpb1,*rpW2,*rpb2;
  float *h,*gi,*gh,*pe0,*pe1,*pre_emb;
  float *po0a,*po0b,*po0c,*pr0a,*pr0b,*pr0c;
  float *po1,*pr1,*po2,*pr2;
  float *states,*h1,*h2;      // h1 aliases gi..pr0c (dead after the scan)
  double *acc;                // [0]=kl [1]=emb [2]=reward
  float *out;
};

__device__ __forceinline__ float4 ld4(const float* p){ return *(const float4*)p; }
__device__ __forceinline__ float elu_f(float x){ return x > 0.f ? x : expm1f(x); }
__device__ __forceinline__ float sigmoid_f(float x){ return 1.f/(1.f+expf(-x)); }
__device__ __forceinline__ float softplus_f(float x){ return x > 20.f ? x : log1pf(expf(x)); }

__device__ __forceinline__ double wave_sum(double v){
  #pragma unroll
  for (int o = 32; o > 0; o >>= 1) v += __shfl_down(v, o, 64);
  return v;
}

// s_t(b, j..j+3) recomputed from po2 (posterior raw) + eps[t]; j % 4 == 0
__device__ __forceinline__ float4 sample4(const Params& p, int b, int j, int t){
  const float4 mu = ld4(p.po2 + b*128 + j);
  const float4 sr = ld4(p.po2 + b*128 + 64 + j);
  const float4 ep = ld4(p.eps + ((long)t*B_ + b)*STOCH_ + j);
  float4 r;
  r.x = mu.x + (softplus_f(sr.x)+1e-4f)*ep.x;
  r.y = mu.y + (softplus_f(sr.y)+1e-4f)*ep.y;
  r.z = mu.z + (softplus_f(sr.z)+1e-4f)*ep.z;
  r.w = mu.w + (softplus_f(sr.w)+1e-4f)*ep.w;
  return r;
}

// 64(M) x 128(N) tile GEMM, 512 threads, double-buffered LDS, 1 barrier/K-iter.
// xld(r, k): float4 of X row r (0..63), k-offset k (mult of 4)
// wld(n, k): float4 of W row n (0..127 tile-local), k-offset k
template<class XLD, class WLD>
__device__ __forceinline__ void gemm_tile(SmemT* sm, XLD xld, WLD wld, int nkt, float acc[4][4])
{
  const int tid = threadIdx.x;
  const int r0 = (tid >> 5) * 4;        // 0..60
  const int c0 = (tid & 31) * 4;        // 0..124
  const int sr = tid & 255;
  const int lr = sr >> 2, q = sr & 3;   // staging: row (0..63), k-quad (0..3)
  const bool lo = tid < 256;
  float4 xa, xb, wa, wb;
  if (lo) { xa = xld(lr, q*4);      xb = xld(lr, 16 + q*4);
            wa = wld(64+lr, q*4);   wb = wld(64+lr, 16 + q*4); }
  else    { wa = wld(lr, q*4);      wb = wld(lr, 16 + q*4); }
  int cur = 0;
  #pragma unroll
  for (int c = 0; c < 4; ++c) {
    if (lo) {
      sm->X[0][q*4+c][lr]      = ((const float*)&xa)[c];
      sm->X[0][16+q*4+c][lr]   = ((const float*)&xb)[c];
      sm->W[0][q*4+c][64+lr]   = ((const float*)&wa)[c];
      sm->W[0][16+q*4+c][64+lr]= ((const float*)&wb)[c];
    } else {
      sm->W[0][q*4+c][lr]      = ((const float*)&wa)[c];
      sm->W[0][16+q*4+c][lr]   = ((const float*)&wb)[c];
    }
  }
  for (int kt = 1; kt < nkt; ++kt) {
    __syncthreads();
    const int kb = kt*TK;
    if (lo) { xa = xld(lr, kb + q*4);    xb = xld(lr, kb + 16 + q*4);
              wa = wld(64+lr, kb + q*4); wb = wld(64+lr, kb + 16 + q*4); }
    else    { wa = wld(lr, kb + q*4);    wb = wld(lr, kb + 16 + q*4); }
    #pragma unroll
    for (int kk = 0; kk < TK; ++kk) {
      const float4 xv = *(const float4*)&sm->X[cur][kk][r0];
      const float4 wv = *(const float4*)&sm->W[cur][kk][c0];
      const float xs_[4] = {xv.x,xv.y,xv.z,xv.w};
      const float ws_[4] = {wv.x,wv.y,wv.z,wv.w};
      #pragma unroll
      for (int i = 0; i < 4; ++i)
        #pragma unroll
        for (int j = 0; j < 4; ++j) acc[i][j] += xs_[i]*ws_[j];
    }
    const int nxt = cur ^ 1;
    #pragma unroll
    for (int c = 0; c < 4; ++c) {
      if (lo) {
        sm->X[nxt][q*4+c][lr]      = ((const float*)&xa)[c];
        sm->X[nxt][16+q*4+c][lr]   = ((const float*)&xb)[c];
        sm->W[nxt][q*4+c][64+lr]   = ((const float*)&wa)[c];
        sm->W[nxt][16+q*4+c][64+lr]= ((const float*)&wb)[c];
      } else {
        sm->W[nxt][q*4+c][lr]      = ((const float*)&wa)[c];
        sm->W[nxt][16+q*4+c][lr]   = ((const float*)&wb)[c];
      }
    }
    cur = nxt;
  }
  __syncthreads();
  #pragma unroll
  for (int kk = 0; kk < TK; ++kk) {
    const float4 xv = *(const float4*)&sm->X[cur][kk][r0];
    const float4 wv = *(const float4*)&sm->W[cur][kk][c0];
    const float xs_[4] = {xv.x,xv.y,xv.z,xv.w};
    const float ws_[4] = {wv.x,wv.y,wv.z,wv.w};
    #pragma unroll
    for (int i = 0; i < 4; ++i)
      #pragma unroll
      for (int j = 0; j < 4; ++j) acc[i][j] += xs_[i]*ws_[j];
  }
  __syncthreads();   // protect LDS reuse by the block's next unit
}

__device__ __forceinline__ void store_tile(const float acc[4][4], const float* bias,
                                           float* C, int ldc, int row0, int col0, bool act)
{
  const int tid = threadIdx.x;
  const int r0 = (tid>>5)*4, c0 = (tid&31)*4;
  const float4 bi = bias ? ld4(bias + col0 + c0) : make_float4(0.f,0.f,0.f,0.f);
  #pragma unroll
  for (int i = 0; i < 4; ++i) {
    float4 v;
    v.x = acc[i][0] + bi.x; v.y = acc[i][1] + bi.y;
    v.z = acc[i][2] + bi.z; v.w = acc[i][3] + bi.w;
    if (act) { v.x=elu_f(v.x); v.y=elu_f(v.y); v.z=elu_f(v.z); v.w=elu_f(v.w); }
    *(float4*)&C[(long)(row0+r0+i)*ldc + col0 + c0] = v;
  }
}

__device__ __forceinline__ double loss_tile(const float acc[4][4], const float* bias,
                                            const float* tgt, int ldt, int row0, int col0)
{
  const int tid = threadIdx.x;
  const int r0 = (tid>>5)*4, c0 = (tid&31)*4;
  const float4 bi = ld4(bias + col0 + c0);
  double ls = 0.0;
  #pragma unroll
  for (int i = 0; i < 4; ++i) {
    const float4 tv = ld4(tgt + (long)(row0+r0+i)*ldt + col0 + c0);
    const float d0 = tv.x - (acc[i][0]+bi.x);
    const float d1 = tv.y - (acc[i][1]+bi.y);
    const float d2 = tv.z - (acc[i][2]+bi.z);
    const float d3 = tv.w - (acc[i][3]+bi.w);
    ls += 0.5*((double)d0*d0 + (double)d1*d1 + (double)d2*d2 + (double)d3*d3);
  }
  return ls;
}

__device__ __forceinline__ void kl_unit(const Params& p, int unit, int nunits)
{
  const int tid = threadIdx.x;
  double ls = 0.0;
  for (int i = unit*NTHR + tid; i < B_*STOCH_; i += nunits*NTHR) {
    const int b = i >> 6, j = i & 63;
    const float qmu  = p.po2[b*128+j];
    const float qstd = softplus_f(p.po2[b*128+64+j]) + 1e-4f;
    const float pmu  = p.pr2[b*128+j];
    const float pstd = softplus_f(p.pr2[b*128+64+j]) + 1e-4f;
    const float dm = qmu - pmu;
    ls += (double)(logf(pstd/qstd) + (qstd*qstd + dm*dm)/(2.f*pstd*pstd) - 0.5f);
  }
  ls = wave_sum(ls);
  if ((tid & 63) == 0) atomicAdd(&p.acc[0], ls);
}

__global__ void __launch_bounds__(NTHR) rssm_kernel(Params p)
{
  cg::grid_group grid = cg::this_grid();
  __shared__ SmemT sm;
  const int blk = blockIdx.x;
  const int tid = threadIdx.x;
  const int G = gridDim.x;

  for (int t = 0; t < T_STEPS; ++t) {
    // ===== S1: gh, gi, pe0, pr2(t-1), states.s(t-1)  [124 units] =====
    for (int u = blk; u < 124; u += G) {
      if (u < 48) {                                   // gh = h @ Whh^T  (N=1536: 12 n-tiles)
        const int mt = u/12, nt = u%12;
        float acc[4][4] = {};
        auto xld = [&](int r,int k){ return ld4(p.h + (mt*64+r)*HID_ + k); };
        auto wld = [&](int n,int k){ return ld4(p.Whh + (long)(nt*128+n)*HID_ + k); };
        gemm_tile(&sm, xld, wld, HID_/TK, acc);
        store_tile(acc, p.bhh, p.gh, G3, mt*64, nt*128, false);
      } else if (u < 96) {                            // gi = [s_{t-1}|a_t] @ Wih^T (K=70, nkt=3)
        const int ti = u-48, mt = ti/12, nt = ti%12;
        float acc[4][4] = {};
        auto xld = [&](int r,int k)->float4{
          const int row = mt*64+r;
          if (k < STOCH_) {
            if (t == 0) return make_float4(0.f,0.f,0.f,0.f);
            return sample4(p, row, k, t-1);
          }
          float v[4];
          #pragma unroll
          for (int c=0;c<4;++c){ const int kk=k+c-STOCH_; v[c] = (kk<ACT_)? p.action[((long)t*B_+row)*ACT_+kk] : 0.f; }
          return make_float4(v[0],v[1],v[2],v[3]);
        };
        auto wld = [&](int n,int k)->float4{
          const int nn = nt*128+n;
          float v[4];
          #pragma unroll
          for (int c=0;c<4;++c){ const int kk=k+c; v[c] = (kk<70)? p.Wih[(long)nn*70+kk] : 0.f; }
          return make_float4(v[0],v[1],v[2],v[3]);
        };
        gemm_tile(&sm, xld, wld, 3, acc);
        store_tile(acc, p.bih, p.gi, G3, mt*64, nt*128, false);
      } else if (u < 112) {                           // pe0 = elu([h|s]_{t-1} @ epW0^T)
        const int ti = u-96, mt = ti/4, nt = ti%4;
        float acc[4][4] = {};
        auto xld = [&](int r,int k)->float4{
          const int row = mt*64+r;
          if (k < HID_) return ld4(p.h + row*HID_ + k);
          if (t == 0) return make_float4(0.f,0.f,0.f,0.f);
          return sample4(p, row, k-HID_, t-1);
        };
        auto wld = [&](int n,int k){ return ld4(p.epW0 + (long)(nt*128+n)*STATE_ + k); };
        gemm_tile(&sm, xld, wld, STATE_/TK, acc);
        store_tile(acc, p.epb0, p.pe0, FEAT_, mt*64, nt*128, true);
      } else if (u < 116) {                           // pr2_{t-1} = pr1 @ stW2^T (N=128: 1 tile)
        if (t > 0) {
          const int mt = u-112;
          float acc[4][4] = {};
          auto xld = [&](int r,int k){ return ld4(p.pr1 + (mt*64+r)*FEAT_ + k); };
          auto wld = [&](int n,int k){ return ld4(p.stW2 + (long)n*FEAT_ + k); };
          gemm_tile(&sm, xld, wld, FEAT_/TK, acc);
          store_tile(acc, p.stb2, p.pr2, 2*STOCH_, mt*64, 0, false);
        }
      } else {                                        // states s-part (t-1): 4096 float4s
        if (t > 0) {
          const int idx = (u-116)*NTHR + tid;         // < 4096
          const int b = idx >> 4, j4 = (idx & 15)*4;
          const float4 sv = sample4(p, b, j4, t-1);
          *(float4*)&p.states[((long)(t-1)*B_ + b)*STATE_ + HID_ + j4] = sv;
        }
      }
    }
    grid.sync();
    // ===== S2: pe1, KL(t-1), GRU combine -> h_t  [84 units] =====
    for (int u = blk; u < 84; u += G) {
      if (u < 16) {                                   // pe1 = elu(pe0 @ epW1^T)
        const int mt = u/4, nt = u%4;
        float acc[4][4] = {};
        auto xld = [&](int r,int k){ return ld4(p.pe0 + (mt*64+r)*FEAT_ + k); };
        auto wld = [&](int n,int k){ return ld4(p.epW1 + (long)(nt*128+n)*FEAT_ + k); };
        gemm_tile(&sm, xld, wld, FEAT_/TK, acc);
        store_tile(acc, p.epb1, p.pe1, FEAT_, mt*64, nt*128, true);
      } else if (u < 20) {                            // KL for t-1
        if (t > 0) kl_unit(p, u-16, 4);
      } else {                                        // GRU combine (float4): 32768 f4s
        const int idx = (u-20)*NTHR + tid;
        const int b = idx >> 7, j4 = (idx & 127)*4;
        const int gb = b*G3 + j4;
        const float4 ir = ld4(p.gi+gb), iz = ld4(p.gi+gb+HID_), in_ = ld4(p.gi+gb+2*HID_);
        const float4 hr = ld4(p.gh+gb), hz = ld4(p.gh+gb+HID_), hn  = ld4(p.gh+gb+2*HID_);
        const float4 ho = ld4(p.h + b*HID_ + j4);
        float4 o;
        { const float r=sigmoid_f(ir.x+hr.x), z=sigmoid_f(iz.x+hz.x), n=tanhf(in_.x+r*hn.x); o.x=(1.f-z)*n+z*ho.x; }
        { const float r=sigmoid_f(ir.y+hr.y), z=sigmoid_f(iz.y+hz.y), n=tanhf(in_.y+r*hn.y); o.y=(1.f-z)*n+z*ho.y; }
        { const float r=sigmoid_f(ir.z+hr.z), z=sigmoid_f(iz.z+hz.z), n=tanhf(in_.z+r*hn.z); o.z=(1.f-z)*n+z*ho.z; }
        { const float r=sigmoid_f(ir.w+hr.w), z=sigmoid_f(iz.w+hz.w), n=tanhf(in_.w+r*hn.w); o.w=(1.f-z)*n+z*ho.w; }
        *(float4*)&p.h[b*HID_ + j4] = o;
        *(float4*)&p.states[((long)t*B_ + b)*STATE_ + j4] = o;
      }
    }
    grid.sync();
    // ===== S3: pre_emb, po0 split-K3  [80 units] =====
    const float* eprev = p.emb + (long)(t>0 ? t-1 : 0)*B_*EMB_;
    for (int u = blk; u < 80; u += G) {
      if (u < 32) {                                   // pre_emb = pe1 @ epW2^T (N=1024: 8 tiles)
        const int mt = u/8, nt = u%8;
        float acc[4][4] = {};
        auto xld = [&](int r,int k){ return ld4(p.pe1 + (mt*64+r)*FEAT_ + k); };
        auto wld = [&](int n,int k){ return ld4(p.epW2 + (long)(nt*128+n)*FEAT_ + k); };
        gemm_tile(&sm, xld, wld, FEAT_/TK, acc);
        store_tile(acc, p.epb2, p.pre_emb, EMB_, mt*64, nt*128, false);
      } else {                                        // po0 partials: c in 0..2, 16 tiles each
        const int v = u-32, c = v/16, ti = v%16, mt = ti/4, nt = ti%4;
        const int kb = c*512;
        float* dst = c==0 ? p.po0a : (c==1 ? p.po0b : p.po0c);
        float acc[4][4] = {};
        auto xld = [&](int r,int k)->float4{
          const int row = mt*64+r; const int kk = kb + k;
          if (kk < HID_) return ld4(p.h + row*HID_ + kk);
          return ld4(eprev + (long)row*EMB_ + (kk-HID_));
        };
        auto wld = [&](int n,int k){ return ld4(p.stW0 + (long)(nt*128+n)*G3 + kb + k); };
        gemm_tile(&sm, xld, wld, 16, acc);
        store_tile(acc, nullptr, dst, FEAT_, mt*64, nt*128, false);
      }
    }
    grid.sync();
    // ===== S4: pr0 split-K3, po1  [64 units] =====
    for (int u = blk; u < 64; u += G) {
      if (u < 48) {
        const int c = u/16, ti = u%16, mt = ti/4, nt = ti%4;
        const int kb = c*512;
        float* dst = c==0 ? p.pr0a : (c==1 ? p.pr0b : p.pr0c);
        float acc[4][4] = {};
        auto xld = [&](int r,int k)->float4{
          const int row = mt*64+r; const int kk = kb + k;
          if (kk < HID_) return ld4(p.h + row*HID_ + kk);
          return ld4(p.pre_emb + (long)row*EMB_ + (kk-HID_));
        };
        auto wld = [&](int n,int k){ return ld4(p.stW0 + (long)(nt*128+n)*G3 + kb + k); };
        gemm_tile(&sm, xld, wld, 16, acc);
        store_tile(acc, nullptr, dst, FEAT_, mt*64, nt*128, false);
      } else {                                        // po1 = elu( elu(Σpo0+b0) @ stW1^T )
        const int ti = u-48, mt = ti/4, nt = ti%4;
        float acc[4][4] = {};
        auto xld = [&](int r,int k)->float4{
          const int o = (mt*64+r)*FEAT_ + k;
          const float4 a = ld4(p.po0a+o), b = ld4(p.po0b+o), cc = ld4(p.po0c+o), bi = ld4(p.stb0+k);
          float4 v;
          v.x = elu_f(a.x+b.x+cc.x+bi.x); v.y = elu_f(a.y+b.y+cc.y+bi.y);
          v.z = elu_f(a.z+b.z+cc.z+bi.z); v.w = elu_f(a.w+b.w+cc.w+bi.w);
          return v;
        };
        auto wld = [&](int n,int k){ return ld4(p.stW1 + (long)(nt*128+n)*FEAT_ + k); };
        gemm_tile(&sm, xld, wld, FEAT_/TK, acc);
        store_tile(acc, p.stb1, p.po1, FEAT_, mt*64, nt*128, true);
      }
    }
    grid.sync();
    // ===== S5: pr1, po2  [20 units] =====
    for (int u = blk; u < 20; u += G) {
      if (u < 16) {
        const int mt = u/4, nt = u%4;
        float acc[4][4] = {};
        auto xld = [&](int r,int k)->float4{
          const int o = (mt*64+r)*FEAT_ + k;
          const float4 a = ld4(p.pr0a+o), b = ld4(p.pr0b+o), cc = ld4(p.pr0c+o), bi = ld4(p.stb0+k);
          float4 v;
          v.x = elu_f(a.x+b.x+cc.x+bi.x); v.y = elu_f(a.y+b.y+cc.y+bi.y);
          v.z = elu_f(a.z+b.z+cc.z+bi.z); v.w = elu_f(a.w+b.w+cc.w+bi.w);
          return v;
        };
        auto wld = [&](int n,int k){ return ld4(p.stW1 + (long)(nt*128+n)*FEAT_ + k); };
        gemm_tile(&sm, xld, wld, FEAT_/TK, acc);
        store_tile(acc, p.stb1, p.pr1, FEAT_, mt*64, nt*128, true);
      } else {                                        // po2 = po1 @ stW2^T
        const int mt = u-16;
        float acc[4][4] = {};
        auto xld = [&](int r,int k){ return ld4(p.po1 + (mt*64+r)*FEAT_ + k); };
        auto wld = [&](int n,int k){ return ld4(p.stW2 + (long)n*FEAT_ + k); };
        gemm_tile(&sm, xld, wld, FEAT_/TK, acc);
        store_tile(acc, p.stb2, p.po2, 2*STOCH_, mt*64, 0, false);
      }
    }
    grid.sync();
  }

  // ===== EP1: pr2(63), states.s(63) =====
  for (int u = blk; u < 12; u += G) {
    if (u < 4) {
      const int mt = u;
      float acc[4][4] = {};
      auto xld = [&](int r,int k){ return ld4(p.pr1 + (mt*64+r)*FEAT_ + k); };
      auto wld = [&](int n,int k){ return ld4(p.stW2 + (long)n*FEAT_ + k); };
      gemm_tile(&sm, xld, wld, FEAT_/TK, acc);
      store_tile(acc, p.stb2, p.pr2, 2*STOCH_, mt*64, 0, false);
    } else {
      const int idx = (u-4)*NTHR + tid;               // < 4096
      const int b = idx >> 4, j4 = (idx & 15)*4;
      const float4 sv = sample4(p, b, j4, 63);
      *(float4*)&p.states[((long)63*B_ + b)*STATE_ + HID_ + j4] = sv;
    }
  }
  grid.sync();

  // ===== emb head: 4 chunks of 4096 rows; KL(63) folded into ch0/P1 =====
  for (int ch = 0; ch < 4; ++ch) {
    const float* xs = p.states + (long)ch*4096*STATE_;
    const int nkl = (ch == 0) ? 4 : 0;
    for (int u = blk; u < 256 + nkl; u += G) {
      if (u < 256) {                                  // h1 = elu(states @ epW0^T)
        const int mt = u/4, nt = u%4;
        float acc[4][4] = {};
        auto xld = [&](int r,int k){ return ld4(xs + (long)(mt*64+r)*STATE_ + k); };
        auto wld = [&](int n,int k){ return ld4(p.epW0 + (long)(nt*128+n)*STATE_ + k); };
        gemm_tile(&sm, xld, wld, STATE_/TK, acc);
        store_tile(acc, p.epb0, p.h1, FEAT_, mt*64, nt*128, true);
      } else {
        kl_unit(p, u-256, 4);                         // KL(63): po2/pr2 are outside the h1 union
      }
    }
    grid.sync();
    for (int u = blk; u < 256; u += G) {              // h2 = elu(h1 @ epW1^T)
      const int mt = u/4, nt = u%4;
      float acc[4][4] = {};
      auto xld = [&](int r,int k){ return ld4(p.h1 + (long)(mt*64+r)*FEAT_ + k); };
      auto wld = [&](int n,int k){ return ld4(p.epW1 + (long)(nt*128+n)*FEAT_ + k); };
      gemm_tile(&sm, xld, wld, FEAT_/TK, acc);
      store_tile(acc, p.epb1, p.h2, FEAT_, mt*64, nt*128, true);
    }
    grid.sync();
    {                                                 // fused emb NLL
      double ls = 0.0;
      const float* tgt = p.emb + (long)ch*4096*EMB_;
      for (int u = blk; u < 512; u += G) {
        const int mt = u/8, nt = u%8;
        float acc[4][4] = {};
        auto xld = [&](int r,int k){ return ld4(p.h2 + (long)(mt*64+r)*FEAT_ + k); };
        auto wld = [&](int n,int k){ return ld4(p.epW2 + (long)(nt*128+n)*FEAT_ + k); };
        gemm_tile(&sm, xld, wld, FEAT_/TK, acc);
        ls += loss_tile(acc, p.epb2, tgt, EMB_, mt*64, nt*128);
      }
      ls = wave_sum(ls);
      if ((tid & 63) == 0) atomicAdd(&p.acc[1], ls);
    }
    grid.sync();
  }

  // ===== reward head: 4 chunks =====
  for (int ch = 0; ch < 4; ++ch) {
    const float* xs = p.states + (long)ch*4096*STATE_;
    for (int u = blk; u < 256; u += G) {
      const int mt = u/4, nt = u%4;
      float acc[4][4] = {};
      auto xld = [&](int r,int k){ return ld4(xs + (long)(mt*64+r)*STATE_ + k); };
      auto wld = [&](int n,int k){ return ld4(p.rpW0 + (long)(nt*128+n)*STATE_ + k); };
      gemm_tile(&sm, xld, wld, STATE_/TK, acc);
      store_tile(acc, p.rpb0, p.h1, FEAT_, mt*64, nt*128, true);
    }
    grid.sync();
    for (int u = blk; u < 256; u += G) {
      const int mt = u/4, nt = u%4;
      float acc[4][4] = {};
      auto xld = [&](int r,int k){ return ld4(p.h1 + (long)(mt*64+r)*FEAT_ + k); };
      auto wld = [&](int n,int k){ return ld4(p.rpW1 + (long)(nt*128+n)*FEAT_ + k); };
      gemm_tile(&sm, xld, wld, FEAT_/TK, acc);
      store_tile(acc, p.rpb1, p.h2, FEAT_, mt*64, nt*128, true);
    }
    grid.sync();
    {                                                 // fused reward NLL (row dot)
      double ls = 0.0;
      const int wid = (blk*NTHR + tid) >> 6, lane = tid & 63;
      const int nw = (G*NTHR) >> 6;
      for (int row = wid; row < 4096; row += nw) {
        float part = 0.f;
        for (int k = lane*4; k < FEAT_; k += 64*4) {
          const float4 hv = ld4(p.h2 + (long)row*FEAT_ + k);
          const float4 wv = ld4(p.rpW2 + k);
          part += hv.x*wv.x + hv.y*wv.y + hv.z*wv.z + hv.w*wv.w;
        }
        #pragma unroll
        for (int o = 32; o > 0; o >>= 1) part += __shfl_down(part, o, 64);
        if (lane == 0) {
          const float mu = part + p.rpb2[0];
          const float d = p.reward[(long)ch*4096 + row] - mu;
          ls += 0.5 * (double)d * (double)d;
        }
      }
      if (lane == 0) atomicAdd(&p.acc[2], ls);
    }
    grid.sync();
  }

  if (blk == 0 && tid == 0) {
    const double k = atomicAdd(&p.acc[0], 0.0);   // device-scope RMW read (cross-XCD safe)
    const double e = atomicAdd(&p.acc[1], 0.0);
    const double r = atomicAdd(&p.acc[2], 0.0);
    const double tot = (k + e + r) / (double)(T_STEPS * B_)
                     + 512.0 * LOG2PI_ + 0.5 * LOG2PI_;
    p.out[0] = (float)tot;
  }
}

extern "C" void kernel_launch(void* const* d_in, const int* in_sizes, int n_in,
                              void* d_out, int out_size, void* d_ws, size_t ws_size,
                              hipStream_t stream) {
  Params p;
  p.emb    = (const float*)d_in[0];
  p.action = (const float*)d_in[1];
  p.reward = (const float*)d_in[2];
  p.eps    = (const float*)d_in[3];
  p.Wih  = (const float*)d_in[4];  p.bih  = (const float*)d_in[5];
  p.Whh  = (const float*)d_in[6];  p.bhh  = (const float*)d_in[7];
  p.stW0 = (const float*)d_in[8];  p.stb0 = (const float*)d_in[9];
  p.stW1 = (const float*)d_in[10]; p.stb1 = (const float*)d_in[11];
  p.stW2 = (const float*)d_in[12]; p.stb2 = (const float*)d_in[13];
  p.epW0 = (const float*)d_in[14]; p.epb0 = (const float*)d_in[15];
  p.epW1 = (const float*)d_in[16]; p.epb1 = (const float*)d_in[17];
  p.epW2 = (const float*)d_in[18]; p.epb2 = (const float*)d_in[19];
  p.rpW0 = (const float*)d_in[20]; p.rpb0 = (const float*)d_in[21];
  p.rpW1 = (const float*)d_in[22]; p.rpb1 = (const float*)d_in[23];
  p.rpW2 = (const float*)d_in[24]; p.rpb2 = (const float*)d_in[25];

  p.acc = (double*)d_ws;
  float* f = (float*)((char*)d_ws + 256);
  p.h = f;          f += 131072;          // zeroed below (h0 = 0)
  float* U = f;     f += 2097152;         // union: step scratch | tail h1 (4096x512)
  p.gi = U;
  p.gh = U + 393216;
  p.pe0 = U + 786432;
  p.pe1 = U + 917504;
  p.pre_emb = U + 1048576;
  p.po0a = U + 1310720;
  p.po0b = U + 1441792;
  p.po0c = U + 1572864;
  p.pr0a = U + 1703936;
  p.pr0b = U + 1835008;
  p.pr0c = U + 1966080;
  p.h1 = U;
  p.po1 = f;        f += 131072;
  p.pr1 = f;        f += 131072;
  p.po2 = f;        f += 32768;
  p.pr2 = f;        f += 32768;
  p.states = f;     f += (long)16384*576;
  p.h2 = f;         f += 2097152;
  p.out = (float*)d_out;
  // total: 256 B + 14,090,240 floats = ~53.8 MiB (< round-1's proven 62.7 MB)

  hipMemsetAsync(d_ws, 0, 256 + (size_t)131072*sizeof(float), stream);

  void* args[] = { &p };
  hipLaunchCooperativeKernel((void*)rssm_kernel, dim3(NBLK), dim3(NTHR), args, 0, stream);
}

// Round 4
// 20161.101 us; speedup vs baseline: 3.1185x; 3.1185x over previous
//
#include <hip/hip_runtime.h>
#include <math.h>

#define T_STEPS 64
#define B_      256
#define EMB_    1024
#define ACT_    6
#define STOCH_  64
#define HID_    512
#define FEAT_   512
#define STATE_  576
#define G3      1536
#define TK      32
#define XPAD    68
#define WPAD    132
#define LOG2PI_ 1.8378770664093453

struct Params {
  const float *emb,*action,*reward,*eps;
  const float *Wih,*bih,*Whh,*bhh;
  const float *stW0,*stb0,*stW1,*stb1,*stW2,*stb2;
  const float *epW0,*epb0,*epW1,*epb1,*epW2,*epb2;
  const float *rpW0,*rpb0,*rpW1,*rpb1,*rpW2,*rpb2;
  float *states;
  double *acc;   // [0]=kl [1]=emb [2]=reward
  float *out;
};

__device__ __forceinline__ float4 ld4(const float* p){ return *(const float4*)p; }
__device__ __forceinline__ float elu_f(float x){ return x > 0.f ? x : expm1f(x); }
__device__ __forceinline__ float sigmoid_f(float x){ return 1.f/(1.f+expf(-x)); }
__device__ __forceinline__ float softplus_f(float x){ return x > 20.f ? x : log1pf(expf(x)); }

__device__ __forceinline__ double wave_sum(double v){
  #pragma unroll
  for (int o = 32; o > 0; o >>= 1) v += __shfl_down(v, o, 64);
  return v;
}

// ---------------- scan kernel: one block per batch row, zero grid syncs ----------------
// 512 threads = 128 clusters of 4 lanes. Cluster c owns output row n = pass*128 + c;
// lane l covers k in {l*4 + 16*j}: 4-lane cluster reads 64 consecutive bytes of W per j
// (cacheline-exact), quad shuffle-reduce at the end.

template<int K>
__device__ __forceinline__ float gemv1(const float* __restrict__ W, const float* x, int n, int l){
  const float* wr = W + (long)n*K + l*4;
  const float* xr = x + l*4;
  float a = 0.f;
  #pragma unroll 8
  for (int j = 0; j < K/16; ++j){
    const float4 w = ld4(wr + 16*j);
    const float4 xv = ld4(xr + 16*j);
    a += w.x*xv.x + w.y*xv.y + w.z*xv.z + w.w*xv.w;
  }
  a += __shfl_xor(a, 1, 64);
  a += __shfl_xor(a, 2, 64);
  return a;
}

// dual GEMV sharing one W stream: head part (k<KH) uses shared x (same partial for both),
// tail part uses xA / xB separately.
template<int KH, int KT>
__device__ __forceinline__ void gemv_dual(const float* __restrict__ W, const float* xh,
                                          const float* xA, const float* xB, int n, int l,
                                          float& yA, float& yB){
  const float* wr = W + (long)n*(KH+KT) + l*4;
  float ah = 0.f, aa = 0.f, ab = 0.f;
  #pragma unroll 4
  for (int j = 0; j < KH/16; ++j){
    const float4 w = ld4(wr + 16*j);
    const float4 xv = ld4(xh + l*4 + 16*j);
    ah += w.x*xv.x + w.y*xv.y + w.z*xv.z + w.w*xv.w;
  }
  const float* wt = wr + KH;
  #pragma unroll 4
  for (int j = 0; j < KT/16; ++j){
    const float4 w = ld4(wt + 16*j);
    const float4 va = ld4(xA + l*4 + 16*j);
    const float4 vb = ld4(xB + l*4 + 16*j);
    aa += w.x*va.x + w.y*va.y + w.z*va.z + w.w*va.w;
    ab += w.x*vb.x + w.y*vb.y + w.z*vb.z + w.w*vb.w;
  }
  float ra = ah + aa, rb = ah + ab;
  ra += __shfl_xor(ra, 1, 64); ra += __shfl_xor(ra, 2, 64);
  rb += __shfl_xor(rb, 1, 64); rb += __shfl_xor(rb, 2, 64);
  yA = ra; yB = rb;
}

// K=70 (gi): rows are 70 floats -> not 16B aligned; scalar loads (tiny traffic)
__device__ __forceinline__ float gemv70(const float* __restrict__ W, const float* x, int n, int l){
  const float* wr = W + (long)n*70;
  float a = 0.f;
  #pragma unroll
  for (int j = 0; j < 4; ++j){
    const int k = l*4 + 16*j;
    #pragma unroll
    for (int c = 0; c < 4; ++c) a += wr[k+c]*x[k+c];
  }
  if (l == 0){
    #pragma unroll
    for (int k = 64; k < 70; ++k) a += wr[k]*x[k];
  }
  a += __shfl_xor(a, 1, 64);
  a += __shfl_xor(a, 2, 64);
  return a;
}

__global__ void __launch_bounds__(512) scan_kernel(Params p)
{
  const int tid = threadIdx.x;
  const int r = blockIdx.x;            // batch row
  const int c = tid >> 2, l = tid & 3; // cluster / lane-in-cluster

  __shared__ __align__(16) float hs[STATE_];   // [h(512) | s(64)]
  __shared__ __align__(16) float sa[80];       // [s(64) | a(6) | 0-pad]
  __shared__ __align__(16) float ep_[EMB_];    // emb_prev row
  __shared__ __align__(16) float pe0[512], pe1[512];
  __shared__ __align__(16) float pemb[EMB_];
  __shared__ __align__(16) float gi[G3], gh[G3];
  __shared__ __align__(16) float po0[512], po1[512], pr0[512], pr1[512];
  __shared__ __align__(16) float po2[128], pr2[128];

  double klacc = 0.0;
  if (tid < STATE_) hs[tid] = 0.f;
  __syncthreads();

  for (int t = 0; t < T_STEPS; ++t){
    // ---- load emb_prev row + build sa = [s_{t-1} | a_t | 0] ----
    {
      const long eb = ((long)(t > 0 ? t-1 : 0)*B_ + r)*EMB_;
      ep_[tid]       = p.emb[eb + tid];
      ep_[tid + 512] = p.emb[eb + 512 + tid];
      if (tid < 80){
        float v = 0.f;
        if (tid < 64)      v = hs[512 + tid];
        else if (tid < 70) v = p.action[((long)t*B_ + r)*ACT_ + (tid - 64)];
        sa[tid] = v;
      }
    }
    __syncthreads();
    // ---- pe0 = elu([h|s]_{t-1} @ epW0^T + b) ----
    #pragma unroll
    for (int ps = 0; ps < 4; ++ps){
      const int n = ps*128 + c;
      const float v = gemv1<STATE_>(p.epW0, hs, n, l);
      if (l == 0) pe0[n] = elu_f(v + p.epb0[n]);
    }
    __syncthreads();
    // ---- pe1 = elu(pe0 @ epW1^T + b) ----
    #pragma unroll
    for (int ps = 0; ps < 4; ++ps){
      const int n = ps*128 + c;
      const float v = gemv1<512>(p.epW1, pe0, n, l);
      if (l == 0) pe1[n] = elu_f(v + p.epb1[n]);
    }
    __syncthreads();
    // ---- pemb = pe1 @ epW2^T + b ; gh = h @ Whh^T + b ; gi = [s|a] @ Wih^T + b ----
    #pragma unroll
    for (int ps = 0; ps < 8; ++ps){
      const int n = ps*128 + c;
      const float v = gemv1<512>(p.epW2, pe1, n, l);
      if (l == 0) pemb[n] = v + p.epb2[n];
    }
    #pragma unroll
    for (int ps = 0; ps < 12; ++ps){
      const int n = ps*128 + c;
      const float v = gemv1<512>(p.Whh, hs, n, l);
      if (l == 0) gh[n] = v + p.bhh[n];
    }
    #pragma unroll
    for (int ps = 0; ps < 12; ++ps){
      const int n = ps*128 + c;
      const float v = gemv70(p.Wih, sa, n, l);
      if (l == 0) gi[n] = v + p.bih[n];
    }
    __syncthreads();
    // ---- GRU combine -> h_t (in place; all hs readers are done) ----
    {
      const int j = tid;
      const float ir = gi[j], iz = gi[512+j], in_ = gi[1024+j];
      const float hr = gh[j], hz = gh[512+j], hn  = gh[1024+j];
      const float rr = sigmoid_f(ir + hr);
      const float z  = sigmoid_f(iz + hz);
      const float nn = tanhf(in_ + rr*hn);
      const float hv = (1.f - z)*nn + z*hs[j];
      hs[j] = hv;
      p.states[((long)t*B_ + r)*STATE_ + j] = hv;
    }
    __syncthreads();
    // ---- st0 dual: head = h_t (shared), tails = emb_prev (posterior) / pemb (prior) ----
    #pragma unroll
    for (int ps = 0; ps < 4; ++ps){
      const int n = ps*128 + c;
      float vA, vB;
      gemv_dual<512, 1024>(p.stW0, hs, ep_, pemb, n, l, vA, vB);
      if (l == 0){
        po0[n] = elu_f(vA + p.stb0[n]);
        pr0[n] = elu_f(vB + p.stb0[n]);
      }
    }
    __syncthreads();
    // ---- st1 dual (one W stream, two x) ----
    #pragma unroll
    for (int ps = 0; ps < 4; ++ps){
      const int n = ps*128 + c;
      float vA, vB;
      gemv_dual<0, 512>(p.stW1, po0, po0, pr0, n, l, vA, vB);
      if (l == 0){
        po1[n] = elu_f(vA + p.stb1[n]);
        pr1[n] = elu_f(vB + p.stb1[n]);
      }
    }
    __syncthreads();
    // ---- st2 dual: N=128 (one pass) ----
    {
      float vA, vB;
      gemv_dual<0, 512>(p.stW2, po1, po1, pr1, c, l, vA, vB);
      if (l == 0){
        po2[c] = vA + p.stb2[c];
        pr2[c] = vB + p.stb2[c];
      }
    }
    __syncthreads();
    // ---- KL(t) + sample s_t ----
    if (tid < 64){
      const int j = tid;
      const float qmu = po2[j],    qsr = po2[64+j];
      const float pmu = pr2[j],    psr = pr2[64+j];
      const float qstd = softplus_f(qsr) + 1e-4f;
      const float pstd = softplus_f(psr) + 1e-4f;
      const float dm = qmu - pmu;
      klacc += (double)(logf(pstd/qstd) + (qstd*qstd + dm*dm)/(2.f*pstd*pstd) - 0.5f);
      const float sv = qmu + qstd * p.eps[((long)t*B_ + r)*STOCH_ + j];
      hs[512 + j] = sv;
      p.states[((long)t*B_ + r)*STATE_ + 512 + j] = sv;
    }
    __syncthreads();
  }

  if (tid < 64){
    const double s = wave_sum(klacc);
    if (tid == 0) atomicAdd(&p.acc[0], s);
  }
}

// ---------------- tail head kernels (plain launches, R3-proven gemm_tile) ----------------

struct SmemT { float X[2][TK][XPAD]; float W[2][TK][WPAD]; };  // 51200 B

template<class XLD, class WLD>
__device__ __forceinline__ void gemm_tile(SmemT* sm, XLD xld, WLD wld, int nkt, float acc[4][4])
{
  const int tid = threadIdx.x;
  const int r0 = (tid >> 5) * 4;
  const int c0 = (tid & 31) * 4;
  const int sr = tid & 255;
  const int lr = sr >> 2, q = sr & 3;
  const bool lo = tid < 256;
  float4 xa, xb, wa, wb;
  if (lo) { xa = xld(lr, q*4);      xb = xld(lr, 16 + q*4);
            wa = wld(64+lr, q*4);   wb = wld(64+lr, 16 + q*4); }
  else    { wa = wld(lr, q*4);      wb = wld(lr, 16 + q*4); }
  int cur = 0;
  #pragma unroll
  for (int c = 0; c < 4; ++c) {
    if (lo) {
      sm->X[0][q*4+c][lr]      = ((const float*)&xa)[c];
      sm->X[0][16+q*4+c][lr]   = ((const float*)&xb)[c];
      sm->W[0][q*4+c][64+lr]   = ((const float*)&wa)[c];
      sm->W[0][16+q*4+c][64+lr]= ((const float*)&wb)[c];
    } else {
      sm->W[0][q*4+c][lr]      = ((const float*)&wa)[c];
      sm->W[0][16+q*4+c][lr]   = ((const float*)&wb)[c];
    }
  }
  for (int kt = 1; kt < nkt; ++kt) {
    __syncthreads();
    const int kb = kt*TK;
    if (lo) { xa = xld(lr, kb + q*4);    xb = xld(lr, kb + 16 + q*4);
              wa = wld(64+lr, kb + q*4); wb = wld(64+lr, kb + 16 + q*4); }
    else    { wa = wld(lr, kb + q*4);    wb = wld(lr, kb + 16 + q*4); }
    #pragma unroll
    for (int kk = 0; kk < TK; ++kk) {
      const float4 xv = *(const float4*)&sm->X[cur][kk][r0];
      const float4 wv = *(const float4*)&sm->W[cur][kk][c0];
      const float xs_[4] = {xv.x,xv.y,xv.z,xv.w};
      const float ws_[4] = {wv.x,wv.y,wv.z,wv.w};
      #pragma unroll
      for (int i = 0; i < 4; ++i)
        #pragma unroll
        for (int j = 0; j < 4; ++j) acc[i][j] += xs_[i]*ws_[j];
    }
    const int nxt = cur ^ 1;
    #pragma unroll
    for (int c = 0; c < 4; ++c) {
      if (lo) {
        sm->X[nxt][q*4+c][lr]      = ((const float*)&xa)[c];
        sm->X[nxt][16+q*4+c][lr]   = ((const float*)&xb)[c];
        sm->W[nxt][q*4+c][64+lr]   = ((const float*)&wa)[c];
        sm->W[nxt][16+q*4+c][64+lr]= ((const float*)&wb)[c];
      } else {
        sm->W[nxt][q*4+c][lr]      = ((const float*)&wa)[c];
        sm->W[nxt][16+q*4+c][lr]   = ((const float*)&wb)[c];
      }
    }
    cur = nxt;
  }
  __syncthreads();
  #pragma unroll
  for (int kk = 0; kk < TK; ++kk) {
    const float4 xv = *(const float4*)&sm->X[cur][kk][r0];
    const float4 wv = *(const float4*)&sm->W[cur][kk][c0];
    const float xs_[4] = {xv.x,xv.y,xv.z,xv.w};
    const float ws_[4] = {wv.x,wv.y,wv.z,wv.w};
    #pragma unroll
    for (int i = 0; i < 4; ++i)
      #pragma unroll
      for (int j = 0; j < 4; ++j) acc[i][j] += xs_[i]*ws_[j];
  }
}

__device__ __forceinline__ void store_tile(const float acc[4][4], const float* bias,
                                           float* C, int ldc, int row0, int col0, bool act)
{
  const int tid = threadIdx.x;
  const int r0 = (tid>>5)*4, c0 = (tid&31)*4;
  const float4 bi = ld4(bias + col0 + c0);
  #pragma unroll
  for (int i = 0; i < 4; ++i) {
    float4 v;
    v.x = acc[i][0] + bi.x; v.y = acc[i][1] + bi.y;
    v.z = acc[i][2] + bi.z; v.w = acc[i][3] + bi.w;
    if (act) { v.x=elu_f(v.x); v.y=elu_f(v.y); v.z=elu_f(v.z); v.w=elu_f(v.w); }
    *(float4*)&C[(long)(row0+r0+i)*ldc + col0 + c0] = v;
  }
}

// Y[4096 x (NT*128)] = act(X @ W^T + b); grid = 64*NT blocks
__global__ void __launch_bounds__(512) mlp_gemm(const float* __restrict__ X, int ldx,
                                                const float* __restrict__ W, int K,
                                                const float* __restrict__ bias,
                                                float* __restrict__ Y, int ldy,
                                                int NT, int act)
{
  __shared__ SmemT sm;
  const int u = blockIdx.x;
  const int mt = u / NT, nt = u % NT;
  float acc[4][4] = {};
  auto xld = [&](int r,int k){ return ld4(X + (long)(mt*64+r)*ldx + k); };
  auto wld = [&](int n,int k){ return ld4(W + (long)(nt*128+n)*K + k); };
  gemm_tile(&sm, xld, wld, K/TK, acc);
  store_tile(acc, bias, Y, ldy, mt*64, nt*128, act != 0);
}

// fused emb NLL: grid = 64*8 blocks over one 4096-row chunk
__global__ void __launch_bounds__(512) emb_loss_k(const float* __restrict__ X,
                                                  const float* __restrict__ W,
                                                  const float* __restrict__ bias,
                                                  const float* __restrict__ tgt,
                                                  double* accp)
{
  __shared__ SmemT sm;
  const int u = blockIdx.x;
  const int mt = u / 8, nt = u % 8;
  float acc[4][4] = {};
  auto xld = [&](int r,int k){ return ld4(X + (long)(mt*64+r)*FEAT_ + k); };
  auto wld = [&](int n,int k){ return ld4(W + (long)(nt*128+n)*FEAT_ + k); };
  gemm_tile(&sm, xld, wld, FEAT_/TK, acc);
  const int tid = threadIdx.x;
  const int r0 = (tid>>5)*4, c0 = (tid&31)*4;
  const float4 bi = ld4(bias + nt*128 + c0);
  double ls = 0.0;
  #pragma unroll
  for (int i = 0; i < 4; ++i) {
    const float4 tv = ld4(tgt + (long)(mt*64+r0+i)*EMB_ + nt*128 + c0);
    const float d0 = tv.x - (acc[i][0]+bi.x);
    const float d1 = tv.y - (acc[i][1]+bi.y);
    const float d2 = tv.z - (acc[i][2]+bi.z);
    const float d3 = tv.w - (acc[i][3]+bi.w);
    ls += 0.5*((double)d0*d0 + (double)d1*d1 + (double)d2*d2 + (double)d3*d3);
  }
  ls = wave_sum(ls);
  if ((tid & 63) == 0) atomicAdd(accp, ls);
}

// reward NLL over one 4096-row chunk: grid = 64 blocks
__global__ void __launch_bounds__(512) rp_loss_k(const float* __restrict__ h2,
                                                 const float* __restrict__ W2,
                                                 const float* __restrict__ b2,
                                                 const float* __restrict__ reward,
                                                 double* accp)
{
  const int tid = threadIdx.x;
  const int lane = tid & 63;
  const int wid = blockIdx.x*8 + (tid >> 6);
  double ls = 0.0;
  for (int row = wid; row < 4096; row += 512) {
    float part = 0.f;
    for (int k = lane*4; k < FEAT_; k += 64*4) {
      const float4 hv = ld4(h2 + (long)row*FEAT_ + k);
      const float4 wv = ld4(W2 + k);
      part += hv.x*wv.x + hv.y*wv.y + hv.z*wv.z + hv.w*wv.w;
    }
    #pragma unroll
    for (int o = 32; o > 0; o >>= 1) part += __shfl_down(part, o, 64);
    if (lane == 0) {
      const float mu = part + b2[0];
      const float d = reward[row] - mu;
      ls += 0.5 * (double)d * (double)d;
    }
  }
  if (lane == 0) atomicAdd(accp, ls);
}

__global__ void final_k(const double* acc, float* out)
{
  const double tot = (acc[0] + acc[1] + acc[2]) / (double)(T_STEPS * B_)
                   + 512.0 * LOG2PI_ + 0.5 * LOG2PI_;
  out[0] = (float)tot;
}

extern "C" void kernel_launch(void* const* d_in, const int* in_sizes, int n_in,
                              void* d_out, int out_size, void* d_ws, size_t ws_size,
                              hipStream_t stream) {
  Params p;
  p.emb    = (const float*)d_in[0];
  p.action = (const float*)d_in[1];
  p.reward = (const float*)d_in[2];
  p.eps    = (const float*)d_in[3];
  p.Wih  = (const float*)d_in[4];  p.bih  = (const float*)d_in[5];
  p.Whh  = (const float*)d_in[6];  p.bhh  = (const float*)d_in[7];
  p.stW0 = (const float*)d_in[8];  p.stb0 = (const float*)d_in[9];
  p.stW1 = (const float*)d_in[10]; p.stb1 = (const float*)d_in[11];
  p.stW2 = (const float*)d_in[12]; p.stb2 = (const float*)d_in[13];
  p.epW0 = (const float*)d_in[14]; p.epb0 = (const float*)d_in[15];
  p.epW1 = (const float*)d_in[16]; p.epb1 = (const float*)d_in[17];
  p.epW2 = (const float*)d_in[18]; p.epb2 = (const float*)d_in[19];
  p.rpW0 = (const float*)d_in[20]; p.rpb0 = (const float*)d_in[21];
  p.rpW1 = (const float*)d_in[22]; p.rpb1 = (const float*)d_in[23];
  p.rpW2 = (const float*)d_in[24]; p.rpb2 = (const float*)d_in[25];

  p.acc = (double*)d_ws;
  float* f = (float*)((char*)d_ws + 256);
  p.states = f;            f += (long)16384 * STATE_;   // 37.75 MB
  float* h1 = f;           f += (long)4096 * FEAT_;     // 8 MB
  float* h2 = f;           f += (long)4096 * FEAT_;     // 8 MB
  p.out = (float*)d_out;
  // total ~54.5 MB

  hipMemsetAsync(d_ws, 0, 256, stream);

  scan_kernel<<<B_, 512, 0, stream>>>(p);

  for (int ch = 0; ch < 4; ++ch) {
    const float* xs = p.states + (long)ch*4096*STATE_;
    mlp_gemm<<<64*4, 512, 0, stream>>>(xs, STATE_, p.epW0, STATE_, p.epb0, h1, FEAT_, 4, 1);
    mlp_gemm<<<64*4, 512, 0, stream>>>(h1, FEAT_, p.epW1, FEAT_, p.epb1, h2, FEAT_, 4, 1);
    emb_loss_k<<<64*8, 512, 0, stream>>>(h2, p.epW2, p.epb2,
                                         p.emb + (long)ch*4096*EMB_, p.acc + 1);
  }
  for (int ch = 0; ch < 4; ++ch) {
    const float* xs = p.states + (long)ch*4096*STATE_;
    mlp_gemm<<<64*4, 512, 0, stream>>>(xs, STATE_, p.rpW0, STATE_, p.rpb0, h1, FEAT_, 4, 1);
    mlp_gemm<<<64*4, 512, 0, stream>>>(h1, FEAT_, p.rpW1, FEAT_, p.rpb1, h2, FEAT_, 4, 1);
    rp_loss_k<<<64, 512, 0, stream>>>(h2, p.rpW2, p.rpb2,
                                      p.reward + (long)ch*4096, p.acc + 2);
  }
  final_k<<<1, 1, 0, stream>>>(p.acc, p.out);
}